// Round 8
// baseline (886.542 us; speedup 1.0000x reference)
//
#include <hip/hip_runtime.h>

typedef unsigned short u16;
typedef __bf16 bf16x8 __attribute__((ext_vector_type(8)));
typedef float f32x4 __attribute__((ext_vector_type(4)));

#define HEADS 16
#define DHEAD 64
#define DIM 1024
#define NTOK 2048
#define BATCH 4
#define CTXD 768
#define SCROSS 77
#define FFIN 4096

__device__ inline float bf2f(u16 v) { return __uint_as_float(((unsigned)v) << 16); }
__device__ inline u16 f2bf(float f) {
    unsigned u = __float_as_uint(f);
    unsigned r = u + 0x7fffu + ((u >> 16) & 1u);
    return (u16)(r >> 16);
}
__device__ inline f32x4 f4zero() { f32x4 v; v[0]=0.f; v[1]=0.f; v[2]=0.f; v[3]=0.f; return v; }
__device__ inline bf16x8 as_bf16x8(uint4 u) { union { uint4 a; bf16x8 b; } c; c.a = u; return c.b; }

// async global->LDS, 16B per lane; per-lane global gather, LDS dest = wave base + lane*16
__device__ inline void gload_lds16(const u16* g, u16* l) {
    __builtin_amdgcn_global_load_lds((const __attribute__((address_space(1))) unsigned*)g,
                                     (__attribute__((address_space(3))) unsigned*)l, 16, 0, 0);
}

#define PRIO1() __builtin_amdgcn_s_setprio(1)
#define PRIO0() __builtin_amdgcn_s_setprio(0)

// ---------------- weight convert+transpose: W[K][N] fp32 -> WT[N][K] bf16 (xscale) ----------------
// remap=1: geglu interleave — 16-col groups alternate a/gate so (a,gate) pairs land in adjacent
// MFMA N-fragments of the geglu epilogue.
__global__ __launch_bounds__(256) void wt_k(const float* __restrict__ W, u16* __restrict__ WT,
                                            int K, int N, float scale, int remap) {
    __shared__ u16 Ts[64][72];
    int k0 = blockIdx.x * 64, n0 = blockIdx.y * 64;
    int t = threadIdx.x;
    int r = t >> 2, c4 = (t & 3) * 16;
    const float* wp = W + (size_t)(k0 + r) * N + n0 + c4;
    #pragma unroll
    for (int j = 0; j < 4; j++) {
        float4 v = *(const float4*)(wp + j * 4);
        Ts[c4 + j * 4 + 0][r] = f2bf(v.x * scale);
        Ts[c4 + j * 4 + 1][r] = f2bf(v.y * scale);
        Ts[c4 + j * 4 + 2][r] = f2bf(v.z * scale);
        Ts[c4 + j * 4 + 3][r] = f2bf(v.w * scale);
    }
    __syncthreads();
    int n = t >> 2, kc = (t & 3) * 16;
    int ng = n0 + n;
    if (remap) ng = ((ng & 4095) >> 4) * 32 + ((ng >> 12) << 4) + (ng & 15);
    u16* op = WT + (size_t)ng * K + k0 + kc;
    *(uint4*)op       = *(const uint4*)&Ts[n][kc];
    *(uint4*)(op + 8) = *(const uint4*)&Ts[n][kc + 8];
}

// ---------------- fp32 -> bf16 convert (ctx) ----------------
__global__ __launch_bounds__(256) void cvt_k(const float* __restrict__ X, u16* __restrict__ Y, int n4) {
    int i = blockIdx.x * 256 + threadIdx.x;
    if (i < n4) {
        float4 v = *(const float4*)(X + (size_t)i * 4);
        uint2 o;
        o.x = (unsigned)f2bf(v.x) | ((unsigned)f2bf(v.y) << 16);
        o.y = (unsigned)f2bf(v.z) | ((unsigned)f2bf(v.w) << 16);
        *(uint2*)(Y + (size_t)i * 4) = o;
    }
}

// ---------------- LayerNorm: fp32 in, bf16 out. One block per row of 1024. ----------------
__global__ __launch_bounds__(256) void ln_k(const float* __restrict__ X, const float* __restrict__ G,
                                            const float* __restrict__ Bt, u16* __restrict__ Y) {
    int row = blockIdx.x;
    int t = threadIdx.x;
    int w = t >> 6, lane = t & 63;
    float4 xv = *(const float4*)(X + (size_t)row * DIM + t * 4);
    float s = xv.x + xv.y + xv.z + xv.w;
    float s2 = xv.x*xv.x + xv.y*xv.y + xv.z*xv.z + xv.w*xv.w;
    for (int off = 1; off < 64; off <<= 1) {
        s  += __shfl_xor(s,  off, 64);
        s2 += __shfl_xor(s2, off, 64);
    }
    __shared__ float rs[4], rs2[4];
    if (lane == 0) { rs[w] = s; rs2[w] = s2; }
    __syncthreads();
    float S_ = rs[0] + rs[1] + rs[2] + rs[3];
    float S2_ = rs2[0] + rs2[1] + rs2[2] + rs2[3];
    float mean = S_ * (1.0f / DIM);
    float var = fmaxf(S2_ * (1.0f / DIM) - mean * mean, 0.f);
    float rstd = rsqrtf(var + 1e-5f);
    int col = t * 4;
    float4 g = *(const float4*)(G + col);
    float4 b = *(const float4*)(Bt + col);
    float y0 = (xv.x - mean) * rstd * g.x + b.x;
    float y1 = (xv.y - mean) * rstd * g.y + b.y;
    float y2 = (xv.z - mean) * rstd * g.z + b.z;
    float y3 = (xv.w - mean) * rstd * g.w + b.w;
    uint2 o;
    o.x = (unsigned)f2bf(y0) | ((unsigned)f2bf(y1) << 16);
    o.y = (unsigned)f2bf(y2) | ((unsigned)f2bf(y3) << 16);
    *(uint2*)(Y + (size_t)row * DIM + col) = o;
}

// ---------------- GEMM m97-style: C[M,N] = A[M,K] (ld lda) * BT[N,K]^T (+bias +resid) ----------------
// 128x128 tile, BK=32, 256 thr = 4 waves, 24 KiB LDS -> ~3 blocks/CU (implicit TLP hides the
// vmcnt0+barrier drain, the proven 912 TF mechanism). resid (if used) has ld == N.
// LDS rows are 64B (4x16B slots): XOR-swizzle slot by (row>>1)&3 (source-side pre-swizzle for
// global_load_lds, same XOR on read) -> conflict-free.
template<typename TC, bool RESID>
__global__ __launch_bounds__(256) void gemm128(const u16* __restrict__ A, int lda,
                                               const u16* __restrict__ BT,
                                               const float* __restrict__ bias, const float* resid,
                                               TC* C, int ldc, int M, int N, int K) {
    __shared__ __align__(16) u16 As[128 * 32];
    __shared__ __align__(16) u16 Bs[128 * 32];
    int m0 = blockIdx.x * 128, n0 = blockIdx.y * 128;
    int t = threadIdx.x;
    int w = t >> 6, lane = t & 63;
    int quad = lane >> 4, l16 = lane & 15;
    int mh = (w & 1) * 64, nh = (w >> 1) * 64;
    f32x4 acc[4][4];
    #pragma unroll
    for (int i = 0; i < 4; i++)
        #pragma unroll
        for (int j = 0; j < 4; j++) acc[i][j] = f4zero();
    int sr = t >> 2;
    int sc8 = (((t & 3) ^ ((sr >> 1) & 3)) * 8);   // inverse-swizzled source col
    int ra0 = min(m0 + sr, M - 1);
    int ra1 = min(m0 + sr + 64, M - 1);
    const u16* ga0 = A + (size_t)ra0 * lda + sc8;
    const u16* ga1 = A + (size_t)ra1 * lda + sc8;
    const u16* gb0 = BT + (size_t)(n0 + sr) * K + sc8;
    const u16* gb1 = BT + (size_t)(n0 + sr + 64) * K + sc8;
    u16* lA0 = &As[w * 512];
    u16* lA1 = &As[2048 + w * 512];
    u16* lB0 = &Bs[w * 512];
    u16* lB1 = &Bs[2048 + w * 512];
    int rq = ((quad ^ ((l16 >> 1) & 3)) * 8);      // swizzled read slot
    for (int k0 = 0; k0 < K; k0 += 32) {
        __syncthreads();
        gload_lds16(ga0 + k0, lA0);
        gload_lds16(ga1 + k0, lA1);
        gload_lds16(gb0 + k0, lB0);
        gload_lds16(gb1 + k0, lB1);
        __syncthreads();
        bf16x8 af[4], bfv[4];
        #pragma unroll
        for (int i = 0; i < 4; i++) {
            af[i]  = as_bf16x8(*(const uint4*)&As[(mh + i * 16 + l16) * 32 + rq]);
            bfv[i] = as_bf16x8(*(const uint4*)&Bs[(nh + i * 16 + l16) * 32 + rq]);
        }
        PRIO1();
        #pragma unroll
        for (int i = 0; i < 4; i++)
            #pragma unroll
            for (int j = 0; j < 4; j++)
                acc[i][j] = __builtin_amdgcn_mfma_f32_16x16x32_bf16(af[i], bfv[j], acc[i][j], 0, 0, 0);
        PRIO0();
    }
    #pragma unroll
    for (int j = 0; j < 4; j++) {
        int gn = n0 + nh + j * 16 + l16;
        float bv = bias ? bias[gn] : 0.f;
        #pragma unroll
        for (int i = 0; i < 4; i++) {
            #pragma unroll
            for (int r = 0; r < 4; r++) {
                int gm = m0 + mh + i * 16 + quad * 4 + r;
                if (gm < M) {
                    float v = acc[i][j][r] + bv;
                    if constexpr (RESID) v += resid[(size_t)gm * N + gn];
                    if constexpr (__is_same(TC, u16)) C[(size_t)gm * ldc + gn] = f2bf(v);
                    else                              C[(size_t)gm * ldc + gn] = v;
                }
            }
        }
    }
}

// ---------------- fused GEGLU GEMM, m97 structure: gb = (P*Wp_a + b_a) * gelu(P*Wp_g + b_g) ----
// Single B-operand over the INTERLEAVED WpT (8192 rows): 16-col groups alternate a/gate, so the
// wave's adjacent N-fragments (j even, j odd) are the (a, gate) pair of output col
// oc = (n0+nh)/2 + jp*16 + l16. Same 24 KiB/3-blocks-per-CU structure as gemm128.
// M=8192, N=8192(interleaved), K=1024 exact — no guards.
__global__ __launch_bounds__(256) void gemm128_geglu(const u16* __restrict__ A,
                                                     const u16* __restrict__ BT,
                                                     const float* __restrict__ bp,
                                                     u16* __restrict__ C) {
    const int K = DIM;
    __shared__ __align__(16) u16 As[128 * 32];
    __shared__ __align__(16) u16 Bs[128 * 32];
    int m0 = blockIdx.x * 128, n0 = blockIdx.y * 128;
    int t = threadIdx.x;
    int w = t >> 6, lane = t & 63;
    int quad = lane >> 4, l16 = lane & 15;
    int mh = (w & 1) * 64, nh = (w >> 1) * 64;
    f32x4 acc[4][4];
    #pragma unroll
    for (int i = 0; i < 4; i++)
        #pragma unroll
        for (int j = 0; j < 4; j++) acc[i][j] = f4zero();
    int sr = t >> 2;
    int sc8 = (((t & 3) ^ ((sr >> 1) & 3)) * 8);   // inverse-swizzled source col
    const u16* ga0 = A + (size_t)(m0 + sr) * K + sc8;
    const u16* ga1 = A + (size_t)(m0 + sr + 64) * K + sc8;
    const u16* gb0 = BT + (size_t)(n0 + sr) * K + sc8;
    const u16* gb1 = BT + (size_t)(n0 + sr + 64) * K + sc8;
    u16* lA0 = &As[w * 512];
    u16* lA1 = &As[2048 + w * 512];
    u16* lB0 = &Bs[w * 512];
    u16* lB1 = &Bs[2048 + w * 512];
    int rq = ((quad ^ ((l16 >> 1) & 3)) * 8);      // swizzled read slot
    for (int k0 = 0; k0 < K; k0 += 32) {
        __syncthreads();
        gload_lds16(ga0 + k0, lA0);
        gload_lds16(ga1 + k0, lA1);
        gload_lds16(gb0 + k0, lB0);
        gload_lds16(gb1 + k0, lB1);
        __syncthreads();
        bf16x8 af[4], bfv[4];
        #pragma unroll
        for (int i = 0; i < 4; i++) {
            af[i]  = as_bf16x8(*(const uint4*)&As[(mh + i * 16 + l16) * 32 + rq]);
            bfv[i] = as_bf16x8(*(const uint4*)&Bs[(nh + i * 16 + l16) * 32 + rq]);
        }
        PRIO1();
        #pragma unroll
        for (int i = 0; i < 4; i++)
            #pragma unroll
            for (int j = 0; j < 4; j++)
                acc[i][j] = __builtin_amdgcn_mfma_f32_16x16x32_bf16(af[i], bfv[j], acc[i][j], 0, 0, 0);
        PRIO0();
    }
    // GEGLU epilogue: fragment pairs (j=2jp, 2jp+1) = (a, gate) of output col oc
    int oc0 = ((n0 + nh) >> 1) + l16;
    #pragma unroll
    for (int jp = 0; jp < 2; jp++) {
        int oc = oc0 + jp * 16;
        float ba = bp[oc];
        float bg = bp[FFIN + oc];
        #pragma unroll
        for (int i = 0; i < 4; i++) {
            #pragma unroll
            for (int r = 0; r < 4; r++) {
                int gm = m0 + mh + i * 16 + quad * 4 + r;
                float a = acc[i][2 * jp][r] + ba;
                float g = acc[i][2 * jp + 1][r] + bg;
                float v = a * (0.5f * g * (1.f + erff(g * 0.70710678118654752f)));
                C[(size_t)gm * FFIN + oc] = f2bf(v);
            }
        }
    }
}

// ---------------- Flash attention v2: max-free log2-softmax ----------------
// LDS tiles row-major, >=128B row stride, XOR slot-swizzle (slot ^= row&7): conflict-free.
// K staged via global_load_lds with inverse-swizzled global source (rule 21).
// T14 V-pipelining: V global loads for tile kt+1 are issued right after QK^T of tile kt
// (latency hides under softmax+PV); the staging window only does transpose+LDS-write.
// Q pre-scaled by 0.125*log2(e) (folded into Wq). Block = (b,h) x 64 q-rows, 4 waves x 16 rows.
__global__ __launch_bounds__(256) void attn_k(const u16* Q, int ldq, const u16* __restrict__ K,
                                              const u16* __restrict__ V, int ldkv,
                                              u16* O, int S) {
    __shared__ __align__(16) u16 Ksh[128 * 64];    // [128 keys][64 d], swizzled
    __shared__ __align__(16) u16 Vt[64 * 128];     // [64 d][128 keys], swizzled
    __shared__ __align__(16) u16 Pb[4][16 * 128];  // per-wave [16 qrow][128 keys], swizzled
    int bh = blockIdx.x;
    int b = bh >> 4, h = bh & 15;
    int q0 = blockIdx.y * 64;
    int t = threadIdx.x;
    int w = t >> 6, lane = t & 63;
    int quad = lane >> 4, l16 = lane & 15;
    int sw = (l16 & 7) << 3;                       // read-side XOR (elements)
    const u16* Qp = Q + ((size_t)b * NTOK + q0) * ldq + h * DHEAD;
    const u16* Kp = K + (size_t)b * S * ldkv + h * DHEAD;
    const u16* Vp = V + (size_t)b * S * ldkv + h * DHEAD;
    bf16x8 qf[2];
    #pragma unroll
    for (int ds = 0; ds < 2; ds++)
        qf[ds] = as_bf16x8(*(const uint4*)(Qp + (size_t)(w * 16 + l16) * ldq + ds * 32 + quad * 8));
    float l_l = 0.f;
    f32x4 o_acc[4];
    #pragma unroll
    for (int dt = 0; dt < 4; dt++) o_acc[dt] = f4zero();
    // K staging: instr i covers rows (i*4+w)*8 + (lane>>3); src d-slot = (lane&7) ^ (row&7)
    int kr8 = lane >> 3;
    int ksl = ((lane & 7) ^ kr8) * 8;
    // V staging: thread handles 4 keys x 8 d
    int vd = (t >> 5) * 8;
    int vk = (t & 31) * 4;
    int nkt = (S + 127) / 128;
    union V4 { uint4 u; u16 e[8]; };
    V4 vrC[4], vrN[4];
    #pragma unroll
    for (int j = 0; j < 4; j++) {                  // prologue: V tile 0 -> regs
        int key = min(vk + j, S - 1);
        vrC[j].u = *(const uint4*)(Vp + (size_t)key * ldkv + vd);
    }
    for (int kt = 0; kt < nkt; kt++) {
        int kbase = kt * 128;
        bool full = (kbase + 128) <= S;
        __syncthreads();
        #pragma unroll
        for (int i = 0; i < 4; i++) {   // stage K: linear LDS dest, inverse-swizzled global src
            int r = min(kbase + (i * 4 + w) * 8 + kr8, S - 1);
            gload_lds16(Kp + (size_t)r * ldkv + ksl, &Ksh[(i * 4 + w) * 512]);
        }
        #pragma unroll
        for (int d = 0; d < 8; d++) {   // write V tile kt (regs -> swizzled LDS)
            int row = vd + d;
            uint2 p;
            p.x = (unsigned)vrC[0].e[d] | ((unsigned)vrC[1].e[d] << 16);
            p.y = (unsigned)vrC[2].e[d] | ((unsigned)vrC[3].e[d] << 16);
            *(uint2*)&Vt[row * 128 + (vk ^ ((row & 7) << 3))] = p;
        }
        __syncthreads();
        // S^T = K·Q^T: 8 subtiles of 16 keys; D[key][qrow]
        f32x4 sc[8];
        PRIO1();
        #pragma unroll
        for (int sub = 0; sub < 8; sub++) {
            const u16* kr = &Ksh[(sub * 16 + l16) * 64];
            bf16x8 kf0 = as_bf16x8(*(const uint4*)(kr + ((quad * 8) ^ sw)));
            bf16x8 kf1 = as_bf16x8(*(const uint4*)(kr + ((32 + quad * 8) ^ sw)));
            f32x4 s = __builtin_amdgcn_mfma_f32_16x16x32_bf16(kf0, qf[0], f4zero(), 0, 0, 0);
            sc[sub] = __builtin_amdgcn_mfma_f32_16x16x32_bf16(kf1, qf[1], s, 0, 0, 0);
        }
        PRIO0();
        if (kt + 1 < nkt) {             // T14: issue next V tile loads; hide under softmax+PV
            #pragma unroll
            for (int j = 0; j < 4; j++) {
                int key = min(kbase + 128 + vk + j, S - 1);
                vrN[j].u = *(const uint4*)(Vp + (size_t)key * ldkv + vd);
            }
        }
        if (!full) {
            #pragma unroll
            for (int sub = 0; sub < 8; sub++)
                #pragma unroll
                for (int r = 0; r < 4; r++)
                    if (kbase + sub * 16 + quad * 4 + r >= S) sc[sub][r] = -1e30f;
        }
        // max-free: p = exp2(s) directly (log2-domain scores; common scale cancels in o/l)
        float psum = 0.f;
        #pragma unroll
        for (int sub = 0; sub < 8; sub++) {
            float p0 = __builtin_amdgcn_exp2f(sc[sub][0]);
            float p1 = __builtin_amdgcn_exp2f(sc[sub][1]);
            float p2 = __builtin_amdgcn_exp2f(sc[sub][2]);
            float p3 = __builtin_amdgcn_exp2f(sc[sub][3]);
            psum += (p0 + p1) + (p2 + p3);
            uint2 pk;
            pk.x = __builtin_amdgcn_perm(__float_as_uint(p1), __float_as_uint(p0), 0x07060302);
            pk.y = __builtin_amdgcn_perm(__float_as_uint(p3), __float_as_uint(p2), 0x07060302);
            *(uint2*)&Pb[w][l16 * 128 + ((sub * 16 + quad * 4) ^ sw)] = pk;
        }
        l_l += psum;
        // PV: P[16q x 128k] (A, own-wave LDS) x V^T (B)
        PRIO1();
        #pragma unroll
        for (int kk = 0; kk < 4; kk++) {
            bf16x8 pf = as_bf16x8(*(const uint4*)&Pb[w][l16 * 128 + ((kk * 32 + quad * 8) ^ sw)]);
            #pragma unroll
            for (int dt = 0; dt < 4; dt++) {
                bf16x8 vf = as_bf16x8(*(const uint4*)&Vt[(dt * 16 + l16) * 128 + ((kk * 32 + quad * 8) ^ sw)]);
                o_acc[dt] = __builtin_amdgcn_mfma_f32_16x16x32_bf16(pf, vf, o_acc[dt], 0, 0, 0);
            }
        }
        PRIO0();
        #pragma unroll
        for (int j = 0; j < 4; j++) vrC[j] = vrN[j];
    }
    float l_tot = l_l;
    l_tot += __shfl_xor(l_tot, 16, 64);
    l_tot += __shfl_xor(l_tot, 32, 64);
    #pragma unroll
    for (int r = 0; r < 4; r++) {
        float lr = __shfl(l_tot, quad * 4 + r, 64);
        float invl = (lr > 0.f) ? (1.f / lr) : 0.f;
        int gq = q0 + w * 16 + quad * 4 + r;
        #pragma unroll
        for (int dt = 0; dt < 4; dt++) {
            O[((size_t)b * NTOK + gq) * ldq + h * DHEAD + dt * 16 + l16] = f2bf(o_acc[dt][r] * invl);
        }
    }
}

extern "C" void kernel_launch(void* const* d_in, const int* in_sizes, int n_in,
                              void* d_out, int out_size, void* d_ws, size_t ws_size,
                              hipStream_t stream) {
    const float* x   = (const float*)d_in[0];
    const float* ctx = (const float*)d_in[1];
    const float* Wq1 = (const float*)d_in[2];
    const float* Wk1 = (const float*)d_in[3];
    const float* Wv1 = (const float*)d_in[4];
    const float* Wo1 = (const float*)d_in[5];
    const float* bo1 = (const float*)d_in[6];
    const float* Wq2 = (const float*)d_in[7];
    const float* Wk2 = (const float*)d_in[8];
    const float* Wv2 = (const float*)d_in[9];
    const float* Wo2 = (const float*)d_in[10];
    const float* bo2 = (const float*)d_in[11];
    const float* Wp  = (const float*)d_in[12];
    const float* bp  = (const float*)d_in[13];
    const float* Wf  = (const float*)d_in[14];
    const float* bfb = (const float*)d_in[15];
    const float* g1  = (const float*)d_in[16];
    const float* b1  = (const float*)d_in[17];
    const float* g2  = (const float*)d_in[18];
    const float* b2  = (const float*)d_in[19];
    const float* g3  = (const float*)d_in[20];
    const float* b3  = (const float*)d_in[21];
    float* out = (float*)d_out;

    const int M = BATCH * NTOK;      // 8192
    const int Mc = BATCH * SCROSS;   // 308
    u16* ws = (u16*)d_ws;
    size_t o = 0;
    u16* WqT1 = ws + o; o += (size_t)DIM * DIM;        // contiguous QKV weight stack:
    u16* WkT1 = ws + o; o += (size_t)DIM * DIM;
    u16* WvT1 = ws + o; o += (size_t)DIM * DIM;
    u16* WoT1 = ws + o; o += (size_t)DIM * DIM;
    u16* WqT2 = ws + o; o += (size_t)DIM * DIM;
    u16* WoT2 = ws + o; o += (size_t)DIM * DIM;
    u16* WkT2 = ws + o; o += (size_t)DIM * CTXD;       // contiguous KV2 stack
    u16* WvT2 = ws + o; o += (size_t)DIM * CTXD;
    u16* WpT  = ws + o; o += (size_t)(2 * FFIN) * DIM; // geglu-interleaved a/gate rows
    u16* WfT  = ws + o; o += (size_t)DIM * FFIN;
    u16* ctxb = ws + o; o += (size_t)Mc * CTXD;
    u16* KVc  = ws + o; o += (size_t)Mc * 2048;        // cross K|V, ld 2048
    u16* P    = ws + o; o += (size_t)M * DIM;          // LN outputs
    u16* QKV  = ws + o; o += (size_t)M * 3072;         // Q|K|V / attn-out, ld 3072
    u16* reg2 = ws + o; o += (size_t)M * DIM * 2;      // X1 (fp32) ; tail of gb
    float* X1 = (float*)reg2;
    u16* gb = QKV;                                     // [8192][4096] overlays QKV+first half of reg2

    dim3 blk(256);
    const float qscale = 0.125f * 1.4426950408889634f;  // 1/sqrt(64) * log2(e)

    wt_k<<<dim3(16, 16), blk, 0, stream>>>(Wq1, WqT1, DIM, DIM, qscale, 0);
    wt_k<<<dim3(16, 16), blk, 0, stream>>>(Wk1, WkT1, DIM, DIM, 1.f, 0);
    wt_k<<<dim3(16, 16), blk, 0, stream>>>(Wv1, WvT1, DIM, DIM, 1.f, 0);
    wt_k<<<dim3(16, 16), blk, 0, stream>>>(Wo1, WoT1, DIM, DIM, 1.f, 0);
    wt_k<<<dim3(16, 16), blk, 0, stream>>>(Wq2, WqT2, DIM, DIM, qscale, 0);
    wt_k<<<dim3(16, 16), blk, 0, stream>>>(Wo2, WoT2, DIM, DIM, 1.f, 0);
    wt_k<<<dim3(12, 16), blk, 0, stream>>>(Wk2, WkT2, CTXD, DIM, 1.f, 0);
    wt_k<<<dim3(12, 16), blk, 0, stream>>>(Wv2, WvT2, CTXD, DIM, 1.f, 0);
    wt_k<<<dim3(16, 128), blk, 0, stream>>>(Wp, WpT, DIM, 2 * FFIN, 1.f, 1);   // interleaved
    wt_k<<<dim3(64, 16), blk, 0, stream>>>(Wf, WfT, FFIN, DIM, 1.f, 0);
    cvt_k<<<dim3((Mc * CTXD / 4 + 255) / 256), blk, 0, stream>>>(ctx, ctxb, Mc * CTXD / 4);

    // --- self attention ---
    ln_k<<<dim3(M), blk, 0, stream>>>(x, g1, b1, P);
    gemm128<u16, false><<<dim3(M / 128, 3072 / 128), blk, 0, stream>>>(
        P, DIM, WqT1, nullptr, nullptr, QKV, 3072, M, 3072, DIM);
    attn_k<<<dim3(BATCH * HEADS, NTOK / 64), blk, 0, stream>>>(
        QKV, 3072, QKV + 1024, QKV + 2048, 3072, QKV, NTOK);
    gemm128<float, true><<<dim3(M / 128, DIM / 128), blk, 0, stream>>>(
        QKV, 3072, WoT1, bo1, x, X1, DIM, M, DIM, DIM);

    // --- cross attention ---
    ln_k<<<dim3(M), blk, 0, stream>>>(X1, g2, b2, P);
    gemm128<u16, false><<<dim3(M / 128, DIM / 128), blk, 0, stream>>>(
        P, DIM, WqT2, nullptr, nullptr, QKV, 3072, M, DIM, DIM);
    gemm128<u16, false><<<dim3((Mc + 127) / 128, 2048 / 128), blk, 0, stream>>>(
        ctxb, CTXD, WkT2, nullptr, nullptr, KVc, 2048, Mc, 2048, CTXD);
    attn_k<<<dim3(BATCH * HEADS, NTOK / 64), blk, 0, stream>>>(
        QKV, 3072, KVc, KVc + 1024, 2048, QKV, SCROSS);
    gemm128<float, true><<<dim3(M / 128, DIM / 128), blk, 0, stream>>>(
        QKV, 3072, WoT2, bo2, X1, out, DIM, M, DIM, DIM);

    // --- GEGLU FF (m97-structure fused Wp+geglu -> gb, then Wf with residual) ---
    ln_k<<<dim3(M), blk, 0, stream>>>(out, g3, b3, P);
    gemm128_geglu<<<dim3(M / 128, (2 * FFIN) / 128), blk, 0, stream>>>(P, WpT, bp, gb);
    gemm128<float, true><<<dim3(M / 128, DIM / 128), blk, 0, stream>>>(
        gb, FFIN, WfT, bfb, out, out, DIM, M, DIM, FFIN);
}

// Round 9
// 862.668 us; speedup vs baseline: 1.0277x; 1.0277x over previous
//
#include <hip/hip_runtime.h>

typedef unsigned short u16;
typedef __bf16 bf16x8 __attribute__((ext_vector_type(8)));
typedef float f32x4 __attribute__((ext_vector_type(4)));

#define HEADS 16
#define DHEAD 64
#define DIM 1024
#define NTOK 2048
#define BATCH 4
#define CTXD 768
#define SCROSS 77
#define FFIN 4096

__device__ inline float bf2f(u16 v) { return __uint_as_float(((unsigned)v) << 16); }
__device__ inline u16 f2bf(float f) {
    unsigned u = __float_as_uint(f);
    unsigned r = u + 0x7fffu + ((u >> 16) & 1u);
    return (u16)(r >> 16);
}
__device__ inline f32x4 f4zero() { f32x4 v; v[0]=0.f; v[1]=0.f; v[2]=0.f; v[3]=0.f; return v; }
__device__ inline bf16x8 as_bf16x8(uint4 u) { union { uint4 a; bf16x8 b; } c; c.a = u; return c.b; }

// async global->LDS, 16B per lane; per-lane global gather, LDS dest = wave base + lane*16
__device__ inline void gload_lds16(const u16* g, u16* l) {
    __builtin_amdgcn_global_load_lds((const __attribute__((address_space(1))) unsigned*)g,
                                     (__attribute__((address_space(3))) unsigned*)l, 16, 0, 0);
}

// ---------------- weight convert+transpose: W[K][N] fp32 -> WT[N][K] bf16 (xscale) ----------------
// remap=1: geglu interleave — 16-col groups alternate a/gate so (a,gate) pairs land in adjacent
// MFMA N-fragments of the gemm256 epilogue.
__global__ __launch_bounds__(256) void wt_k(const float* __restrict__ W, u16* __restrict__ WT,
                                            int K, int N, float scale, int remap) {
    __shared__ u16 Ts[64][72];
    int k0 = blockIdx.x * 64, n0 = blockIdx.y * 64;
    int t = threadIdx.x;
    int r = t >> 2, c4 = (t & 3) * 16;
    const float* wp = W + (size_t)(k0 + r) * N + n0 + c4;
    #pragma unroll
    for (int j = 0; j < 4; j++) {
        float4 v = *(const float4*)(wp + j * 4);
        Ts[c4 + j * 4 + 0][r] = f2bf(v.x * scale);
        Ts[c4 + j * 4 + 1][r] = f2bf(v.y * scale);
        Ts[c4 + j * 4 + 2][r] = f2bf(v.z * scale);
        Ts[c4 + j * 4 + 3][r] = f2bf(v.w * scale);
    }
    __syncthreads();
    int n = t >> 2, kc = (t & 3) * 16;
    int ng = n0 + n;
    if (remap) ng = ((ng & 4095) >> 4) * 32 + ((ng >> 12) << 4) + (ng & 15);
    u16* op = WT + (size_t)ng * K + k0 + kc;
    *(uint4*)op       = *(const uint4*)&Ts[n][kc];
    *(uint4*)(op + 8) = *(const uint4*)&Ts[n][kc + 8];
}

// ---------------- fp32 -> bf16 convert (ctx) ----------------
__global__ __launch_bounds__(256) void cvt_k(const float* __restrict__ X, u16* __restrict__ Y, int n4) {
    int i = blockIdx.x * 256 + threadIdx.x;
    if (i < n4) {
        float4 v = *(const float4*)(X + (size_t)i * 4);
        uint2 o;
        o.x = (unsigned)f2bf(v.x) | ((unsigned)f2bf(v.y) << 16);
        o.y = (unsigned)f2bf(v.z) | ((unsigned)f2bf(v.w) << 16);
        *(uint2*)(Y + (size_t)i * 4) = o;
    }
}

// ---------------- LayerNorm: fp32 in, bf16 out. One block per row of 1024. ----------------
__global__ __launch_bounds__(256) void ln_k(const float* __restrict__ X, const float* __restrict__ G,
                                            const float* __restrict__ Bt, u16* __restrict__ Y) {
    int row = blockIdx.x;
    int t = threadIdx.x;
    int w = t >> 6, lane = t & 63;
    float4 xv = *(const float4*)(X + (size_t)row * DIM + t * 4);
    float s = xv.x + xv.y + xv.z + xv.w;
    float s2 = xv.x*xv.x + xv.y*xv.y + xv.z*xv.z + xv.w*xv.w;
    for (int off = 1; off < 64; off <<= 1) {
        s  += __shfl_xor(s,  off, 64);
        s2 += __shfl_xor(s2, off, 64);
    }
    __shared__ float rs[4], rs2[4];
    if (lane == 0) { rs[w] = s; rs2[w] = s2; }
    __syncthreads();
    float S_ = rs[0] + rs[1] + rs[2] + rs[3];
    float S2_ = rs2[0] + rs2[1] + rs2[2] + rs2[3];
    float mean = S_ * (1.0f / DIM);
    float var = fmaxf(S2_ * (1.0f / DIM) - mean * mean, 0.f);
    float rstd = rsqrtf(var + 1e-5f);
    int col = t * 4;
    float4 g = *(const float4*)(G + col);
    float4 b = *(const float4*)(Bt + col);
    float y0 = (xv.x - mean) * rstd * g.x + b.x;
    float y1 = (xv.y - mean) * rstd * g.y + b.y;
    float y2 = (xv.z - mean) * rstd * g.z + b.z;
    float y3 = (xv.w - mean) * rstd * g.w + b.w;
    uint2 o;
    o.x = (unsigned)f2bf(y0) | ((unsigned)f2bf(y1) << 16);
    o.y = (unsigned)f2bf(y2) | ((unsigned)f2bf(y3) << 16);
    *(uint2*)(Y + (size_t)row * DIM + col) = o;
}

// ---------------- GEMM m97-style: C[M,N] = A[M,K] (ld lda) * BT[N,K]^T (+bias +resid) ----------------
// 128x128 tile, BK=32, 256 thr = 4 waves. resid (if used) has ld == N. Kept for N<=1024 shapes.
template<typename TC, bool RESID>
__global__ __launch_bounds__(256) void gemm128(const u16* __restrict__ A, int lda,
                                               const u16* __restrict__ BT,
                                               const float* __restrict__ bias, const float* resid,
                                               TC* C, int ldc, int M, int N, int K) {
    __shared__ __align__(16) u16 As[128 * 32];
    __shared__ __align__(16) u16 Bs[128 * 32];
    int m0 = blockIdx.x * 128, n0 = blockIdx.y * 128;
    int t = threadIdx.x;
    int w = t >> 6, lane = t & 63;
    int quad = lane >> 4, l16 = lane & 15;
    int mh = (w & 1) * 64, nh = (w >> 1) * 64;
    f32x4 acc[4][4];
    #pragma unroll
    for (int i = 0; i < 4; i++)
        #pragma unroll
        for (int j = 0; j < 4; j++) acc[i][j] = f4zero();
    int sr = t >> 2;
    int sc8 = (((t & 3) ^ ((sr >> 1) & 3)) * 8);   // inverse-swizzled source col
    int ra0 = min(m0 + sr, M - 1);
    int ra1 = min(m0 + sr + 64, M - 1);
    const u16* ga0 = A + (size_t)ra0 * lda + sc8;
    const u16* ga1 = A + (size_t)ra1 * lda + sc8;
    const u16* gb0 = BT + (size_t)(n0 + sr) * K + sc8;
    const u16* gb1 = BT + (size_t)(n0 + sr + 64) * K + sc8;
    u16* lA0 = &As[w * 512];
    u16* lA1 = &As[2048 + w * 512];
    u16* lB0 = &Bs[w * 512];
    u16* lB1 = &Bs[2048 + w * 512];
    int rq = ((quad ^ ((l16 >> 1) & 3)) * 8);      // swizzled read slot
    for (int k0 = 0; k0 < K; k0 += 32) {
        __syncthreads();
        gload_lds16(ga0 + k0, lA0);
        gload_lds16(ga1 + k0, lA1);
        gload_lds16(gb0 + k0, lB0);
        gload_lds16(gb1 + k0, lB1);
        __syncthreads();
        bf16x8 af[4], bfv[4];
        #pragma unroll
        for (int i = 0; i < 4; i++) {
            af[i]  = as_bf16x8(*(const uint4*)&As[(mh + i * 16 + l16) * 32 + rq]);
            bfv[i] = as_bf16x8(*(const uint4*)&Bs[(nh + i * 16 + l16) * 32 + rq]);
        }
        #pragma unroll
        for (int i = 0; i < 4; i++)
            #pragma unroll
            for (int j = 0; j < 4; j++)
                acc[i][j] = __builtin_amdgcn_mfma_f32_16x16x32_bf16(af[i], bfv[j], acc[i][j], 0, 0, 0);
    }
    #pragma unroll
    for (int j = 0; j < 4; j++) {
        int gn = n0 + nh + j * 16 + l16;
        float bv = bias ? bias[gn] : 0.f;
        #pragma unroll
        for (int i = 0; i < 4; i++) {
            #pragma unroll
            for (int r = 0; r < 4; r++) {
                int gm = m0 + mh + i * 16 + quad * 4 + r;
                if (gm < M) {
                    float v = acc[i][j][r] + bv;
                    if constexpr (RESID) v += resid[(size_t)gm * N + gn];
                    if constexpr (__is_same(TC, u16)) C[(size_t)gm * ldc + gn] = f2bf(v);
                    else                              C[(size_t)gm * ldc + gn] = v;
                }
            }
        }
    }
}

// ================= GEMM 256x256, BK=64, overlapped-read pipeline (measured best: 727 TF) =========
// A[M,1024] bf16 (ld 1024), BT[N,1024] bf16 (ld 1024). Exact tiles only. 512 thr = 8 waves (2Mx4N).
// Every ds_read is issued >=1 MFMA-cluster before its consuming MFMA (counted lgkm waits), so the
// LDS pipe overlaps the MFMA pipe. Only 2 barriers per tile (entry, mid).
// EPI 0: plain bf16 store, ld=LDC.  EPI 1: GEGLU over interleaved Wp (fj even=a, odd=gate).

#define BAR() __builtin_amdgcn_s_barrier()
#define SB0() __builtin_amdgcn_sched_barrier(0)
#define PRIO1() __builtin_amdgcn_s_setprio(1)
#define PRIO0() __builtin_amdgcn_s_setprio(0)
#define WAIT_VM6() asm volatile("s_waitcnt vmcnt(6)" ::: "memory")
#define WAIT_VM4() asm volatile("s_waitcnt vmcnt(4)" ::: "memory")
#define WAIT_VM0() asm volatile("s_waitcnt vmcnt(0)" ::: "memory")
#define WAIT_LGKM0() asm volatile("s_waitcnt lgkmcnt(0)" ::: "memory")
#define WAIT_LGKM8() asm volatile("s_waitcnt lgkmcnt(8)" ::: "memory")

#define STAGE_A_R(P, h, q, TAU) gload_lds16(gA + (size_t)((h) * 128 + (q) * 64) * 1024 + (TAU) * 64, \
                                            lA + (P) * 16384 + (h) * 8192 + (q) * 4096)
#define STAGE_B_R(P, h, q, TAU) gload_lds16(gB + (size_t)((h) * 128 + (q) * 64) * 1024 + (TAU) * 64, \
                                            lB + (P) * 16384 + (h) * 8192 + (q) * 4096)
#define RD_A(P, fi, ks) as_bf16x8(*(const uint4*)(rdA + (P) * 32768 + (fi) * 2048 + ((ks) ? o1 : o0)))
#define RD_B(P, fj, ks) as_bf16x8(*(const uint4*)(rdB + (P) * 32768 + (fj) * 2048 + ((ks) ? o1 : o0)))
#define MM(ai, aj, av, bv) acc[ai][aj] = __builtin_amdgcn_mfma_f32_16x16x32_bf16(av, bv, acc[ai][aj], 0, 0, 0)

#define Q00() do { \
    MM(0,0,A0r[0][0],B0r[0][0]); MM(1,0,A0r[1][0],B0r[0][0]); MM(2,0,A0r[2][0],B0r[0][0]); MM(3,0,A0r[3][0],B0r[0][0]); \
    MM(0,1,A0r[0][0],B0r[1][0]); MM(1,1,A0r[1][0],B0r[1][0]); MM(2,1,A0r[2][0],B0r[1][0]); MM(3,1,A0r[3][0],B0r[1][0]); \
    MM(0,0,A0r[0][1],B0r[0][1]); MM(1,0,A0r[1][1],B0r[0][1]); MM(2,0,A0r[2][1],B0r[0][1]); MM(3,0,A0r[3][1],B0r[0][1]); \
    MM(0,1,A0r[0][1],B0r[1][1]); MM(1,1,A0r[1][1],B0r[1][1]); MM(2,1,A0r[2][1],B0r[1][1]); MM(3,1,A0r[3][1],B0r[1][1]); \
} while (0)
#define Q01() do { \
    MM(0,2,A0r[0][0],B1r[0][0]); MM(1,2,A0r[1][0],B1r[0][0]); MM(2,2,A0r[2][0],B1r[0][0]); MM(3,2,A0r[3][0],B1r[0][0]); \
    MM(0,3,A0r[0][0],B1r[1][0]); MM(1,3,A0r[1][0],B1r[1][0]); MM(2,3,A0r[2][0],B1r[1][0]); MM(3,3,A0r[3][0],B1r[1][0]); \
    MM(0,2,A0r[0][1],B1r[0][1]); MM(1,2,A0r[1][1],B1r[0][1]); MM(2,2,A0r[2][1],B1r[0][1]); MM(3,2,A0r[3][1],B1r[0][1]); \
    MM(0,3,A0r[0][1],B1r[1][1]); MM(1,3,A0r[1][1],B1r[1][1]); MM(2,3,A0r[2][1],B1r[1][1]); MM(3,3,A0r[3][1],B1r[1][1]); \
} while (0)
#define Q10() do { \
    MM(4,0,A1r[0][0],B0r[0][0]); MM(5,0,A1r[1][0],B0r[0][0]); MM(6,0,A1r[2][0],B0r[0][0]); MM(7,0,A1r[3][0],B0r[0][0]); \
    MM(4,1,A1r[0][0],B0r[1][0]); MM(5,1,A1r[1][0],B0r[1][0]); MM(6,1,A1r[2][0],B0r[1][0]); MM(7,1,A1r[3][0],B0r[1][0]); \
    MM(4,0,A1r[0][1],B0r[0][1]); MM(5,0,A1r[1][1],B0r[0][1]); MM(6,0,A1r[2][1],B0r[0][1]); MM(7,0,A1r[3][1],B0r[0][1]); \
    MM(4,1,A1r[0][1],B0r[1][1]); MM(5,1,A1r[1][1],B0r[1][1]); MM(6,1,A1r[2][1],B0r[1][1]); MM(7,1,A1r[3][1],B0r[1][1]); \
} while (0)
#define Q11() do { \
    MM(4,2,A1r[0][0],B1r[0][0]); MM(5,2,A1r[1][0],B1r[0][0]); MM(6,2,A1r[2][0],B1r[0][0]); MM(7,2,A1r[3][0],B1r[0][0]); \
    MM(4,3,A1r[0][0],B1r[1][0]); MM(5,3,A1r[1][0],B1r[1][0]); MM(6,3,A1r[2][0],B1r[1][0]); MM(7,3,A1r[3][0],B1r[1][0]); \
    MM(4,2,A1r[0][1],B1r[0][1]); MM(5,2,A1r[1][1],B1r[0][1]); MM(6,2,A1r[2][1],B1r[0][1]); MM(7,2,A1r[3][1],B1r[0][1]); \
    MM(4,3,A1r[0][1],B1r[1][1]); MM(5,3,A1r[1][1],B1r[1][1]); MM(6,3,A1r[2][1],B1r[1][1]); MM(7,3,A1r[3][1],B1r[1][1]); \
} while (0)

#define TILEX(P, S0, S1, T, MIDW, ENDW, LAST) do {                                    \
    B1r[0][0] = RD_B(P, 2, 0); B1r[0][1] = RD_B(P, 2, 1);                             \
    B1r[1][0] = RD_B(P, 3, 0); B1r[1][1] = RD_B(P, 3, 1);                             \
    if (S0) { STAGE_B_R((P) ^ 1, 1, 0, (T) + 1); STAGE_B_R((P) ^ 1, 1, 1, (T) + 1); } \
    SB0(); PRIO1(); Q00(); PRIO0(); SB0();                                            \
    A1r[0][0] = RD_A(P, 4, 0); A1r[0][1] = RD_A(P, 4, 1);                             \
    A1r[1][0] = RD_A(P, 5, 0); A1r[1][1] = RD_A(P, 5, 1);                             \
    A1r[2][0] = RD_A(P, 6, 0); A1r[2][1] = RD_A(P, 6, 1);                             \
    A1r[3][0] = RD_A(P, 7, 0); A1r[3][1] = RD_A(P, 7, 1);                             \
    if (S1) { STAGE_A_R(P, 0, 0, (T) + 2); STAGE_A_R(P, 1, 0, (T) + 2); }             \
    WAIT_LGKM8(); SB0(); PRIO1(); Q01(); PRIO0(); SB0();                              \
    WAIT_LGKM0();                                                                     \
    if (!(LAST)) { MIDW; BAR(); }                                                     \
    SB0();                                                                            \
    if (!(LAST)) {                                                                    \
        A0r[0][0] = RD_A((P) ^ 1, 0, 0); A0r[0][1] = RD_A((P) ^ 1, 0, 1);             \
        A0r[1][0] = RD_A((P) ^ 1, 1, 0); A0r[1][1] = RD_A((P) ^ 1, 1, 1);             \
        A0r[2][0] = RD_A((P) ^ 1, 2, 0); A0r[2][1] = RD_A((P) ^ 1, 2, 1);             \
        A0r[3][0] = RD_A((P) ^ 1, 3, 0); A0r[3][1] = RD_A((P) ^ 1, 3, 1);             \
    }                                                                                 \
    if (S1) { STAGE_B_R(P, 0, 0, (T) + 2); STAGE_B_R(P, 0, 1, (T) + 2); }             \
    SB0(); PRIO1(); Q10(); PRIO0(); SB0();                                            \
    if (!(LAST)) {                                                                    \
        B0r[0][0] = RD_B((P) ^ 1, 0, 0); B0r[0][1] = RD_B((P) ^ 1, 0, 1);             \
        B0r[1][0] = RD_B((P) ^ 1, 1, 0); B0r[1][1] = RD_B((P) ^ 1, 1, 1);             \
    }                                                                                 \
    if (S1) { STAGE_A_R(P, 0, 1, (T) + 2); STAGE_A_R(P, 1, 1, (T) + 2); }             \
    SB0(); PRIO1(); Q11(); PRIO0(); SB0();                                            \
    if (!(LAST)) { WAIT_LGKM0(); ENDW; BAR(); }                                       \
    SB0();                                                                            \
} while (0)

template<int NBY, int LDC, int EPI>
__global__ __launch_bounds__(512, 2) void gemm256(const u16* __restrict__ A,
                                                  const u16* __restrict__ BT,
                                                  const float* __restrict__ bias,
                                                  u16* __restrict__ C) {
    __shared__ __align__(16) u16 As[2][16384];
    __shared__ __align__(16) u16 Bs[2][16384];
    int t = threadIdx.x;
    int w = t >> 6, lane = t & 63;
    int quad = lane >> 4, l16 = lane & 15;
    int wm = w >> 2, wn = w & 3;
    int bid = blockIdx.x;
    int cpx = (int)gridDim.x >> 3;
    int swz = (bid & 7) * cpx + (bid >> 3);
    int bx = swz / NBY, by = swz % NBY;
    int m0 = bx << 8, n0 = by << 8;

    int ar = t >> 3;
    int ac = (((t & 7) ^ (ar & 7)) << 3);
    const u16* gA = A + (size_t)(m0 + ar) * 1024 + ac;
    const u16* gB = BT + (size_t)(n0 + ar) * 1024 + ac;
    u16* lA = &As[0][0] + (w << 9);
    u16* lB = &Bs[0][0] + (w << 9);
    const char* rdA = (const char*)&As[0][0] + (((wm << 7) + l16) << 7);
    const char* rdB = (const char*)&Bs[0][0] + (((wn << 6) + l16) << 7);
    int o0 = (quad << 4) ^ ((l16 & 7) << 4);
    int o1 = o0 ^ 64;

    f32x4 acc[8][4];
    #pragma unroll
    for (int i = 0; i < 8; i++)
        #pragma unroll
        for (int j = 0; j < 4; j++) acc[i][j] = f4zero();

    STAGE_A_R(0, 0, 0, 0); STAGE_A_R(0, 1, 0, 0);       // t0.Aq0
    STAGE_B_R(0, 0, 0, 0); STAGE_B_R(0, 0, 1, 0);       // t0.Bh0
    STAGE_A_R(0, 0, 1, 0); STAGE_A_R(0, 1, 1, 0);       // t0.Aq1
    STAGE_B_R(0, 1, 0, 0); STAGE_B_R(0, 1, 1, 0);       // t0.Bh1
    STAGE_A_R(1, 0, 0, 1); STAGE_A_R(1, 1, 0, 1);       // t1.Aq0
    STAGE_B_R(1, 0, 0, 1); STAGE_B_R(1, 0, 1, 1);       // t1.Bh0
    STAGE_A_R(1, 0, 1, 1); STAGE_A_R(1, 1, 1, 1);       // t1.Aq1
    WAIT_VM6();
    BAR();
    bf16x8 A0r[4][2], A1r[4][2], B0r[2][2], B1r[2][2];
    A0r[0][0] = RD_A(0, 0, 0); A0r[0][1] = RD_A(0, 0, 1);
    A0r[1][0] = RD_A(0, 1, 0); A0r[1][1] = RD_A(0, 1, 1);
    A0r[2][0] = RD_A(0, 2, 0); A0r[2][1] = RD_A(0, 2, 1);
    A0r[3][0] = RD_A(0, 3, 0); A0r[3][1] = RD_A(0, 3, 1);
    B0r[0][0] = RD_B(0, 0, 0); B0r[0][1] = RD_B(0, 0, 1);
    B0r[1][0] = RD_B(0, 1, 0); B0r[1][1] = RD_B(0, 1, 1);
    WAIT_LGKM0();
    BAR();

    #pragma unroll 1
    for (int tt = 0; tt < 14; tt += 2) {
        TILEX(0, 1, 1, tt,     WAIT_VM6(), WAIT_VM6(), 0);
        TILEX(1, 1, 1, tt + 1, WAIT_VM6(), WAIT_VM6(), 0);
    }
    TILEX(0, 1, 0, 14, WAIT_VM4(), WAIT_VM0(), 0);
    TILEX(1, 0, 0, 15, (void)0, (void)0, 1);

    if constexpr (EPI == 0) {
        int gm0 = m0 + wm * 128 + quad * 4;
        int gn0 = n0 + wn * 64 + l16;
        #pragma unroll
        for (int fi = 0; fi < 8; fi++)
            #pragma unroll
            for (int fj = 0; fj < 4; fj++)
                #pragma unroll
                for (int r = 0; r < 4; r++)
                    C[(size_t)(gm0 + fi * 16 + r) * LDC + gn0 + fj * 16] = f2bf(acc[fi][fj][r]);
    } else {
        int gm0 = m0 + wm * 128 + quad * 4;
        int oc0 = (n0 >> 1) + wn * 32 + l16;
        #pragma unroll
        for (int jp = 0; jp < 2; jp++) {
            int oc = oc0 + jp * 16;
            float ba = bias[oc];
            float bg = bias[FFIN + oc];
            #pragma unroll
            for (int fi = 0; fi < 8; fi++)
                #pragma unroll
                for (int r = 0; r < 4; r++) {
                    float a = acc[fi][2 * jp][r] + ba;
                    float g = acc[fi][2 * jp + 1][r] + bg;
                    float v = a * (0.5f * g * (1.f + erff(g * 0.70710678118654752f)));
                    C[(size_t)(gm0 + fi * 16 + r) * LDC + oc] = f2bf(v);
                }
        }
    }
}

// ---------------- Flash attention v2: max-free log2-softmax, QBLK=128 ----------------
// 4 waves x 32 q-rows (2 fragments of 16). K/V staged ONCE per 128 q-rows (2x amortization vs
// QBLK=64), halving staging + barrier cost per unit work. LDS tiles row-major, >=128B row stride,
// XOR slot-swizzle (slot ^= row&7): conflict-free (P-row = f*16+l16 => row&7 = l16&7, sw intact).
// K staged via global_load_lds with inverse-swizzled global source (rule 21). T14 V-pipelining.
// Q pre-scaled by 0.125*log2(e) (folded into Wq).
__global__ __launch_bounds__(256) void attn_k(const u16* Q, int ldq, const u16* __restrict__ K,
                                              const u16* __restrict__ V, int ldkv,
                                              u16* O, int S) {
    __shared__ __align__(16) u16 Ksh[128 * 64];    // [128 keys][64 d], swizzled
    __shared__ __align__(16) u16 Vt[64 * 128];     // [64 d][128 keys], swizzled
    __shared__ __align__(16) u16 Pb[4][32 * 128];  // per-wave [32 qrow][128 keys], swizzled
    int bh = blockIdx.x;
    int b = bh >> 4, h = bh & 15;
    int q0 = blockIdx.y * 128;
    int t = threadIdx.x;
    int w = t >> 6, lane = t & 63;
    int quad = lane >> 4, l16 = lane & 15;
    int sw = (l16 & 7) << 3;                       // read-side XOR (elements)
    const u16* Qp = Q + ((size_t)b * NTOK + q0) * ldq + h * DHEAD;
    const u16* Kp = K + (size_t)b * S * ldkv + h * DHEAD;
    const u16* Vp = V + (size_t)b * S * ldkv + h * DHEAD;
    bf16x8 qf[2][2];
    #pragma unroll
    for (int f = 0; f < 2; f++)
        #pragma unroll
        for (int ds = 0; ds < 2; ds++)
            qf[f][ds] = as_bf16x8(*(const uint4*)(Qp + (size_t)(w * 32 + f * 16 + l16) * ldq + ds * 32 + quad * 8));
    float l_l[2] = {0.f, 0.f};
    f32x4 o_acc[2][4];
    #pragma unroll
    for (int f = 0; f < 2; f++)
        #pragma unroll
        for (int dt = 0; dt < 4; dt++) o_acc[f][dt] = f4zero();
    // K staging: instr i covers rows (i*4+w)*8 + (lane>>3); src d-slot = (lane&7) ^ (row&7)
    int kr8 = lane >> 3;
    int ksl = ((lane & 7) ^ kr8) * 8;
    // V staging: thread handles 4 keys x 8 d
    int vd = (t >> 5) * 8;
    int vk = (t & 31) * 4;
    int nkt = (S + 127) / 128;
    union V4 { uint4 u; u16 e[8]; };
    V4 vrC[4], vrN[4];
    #pragma unroll
    for (int j = 0; j < 4; j++) {                  // prologue: V tile 0 -> regs
        int key = min(vk + j, S - 1);
        vrC[j].u = *(const uint4*)(Vp + (size_t)key * ldkv + vd);
    }
    for (int kt = 0; kt < nkt; kt++) {
        int kbase = kt * 128;
        bool full = (kbase + 128) <= S;
        __syncthreads();
        #pragma unroll
        for (int i = 0; i < 4; i++) {   // stage K: linear LDS dest, inverse-swizzled global src
            int r = min(kbase + (i * 4 + w) * 8 + kr8, S - 1);
            gload_lds16(Kp + (size_t)r * ldkv + ksl, &Ksh[(i * 4 + w) * 512]);
        }
        #pragma unroll
        for (int d = 0; d < 8; d++) {   // write V tile kt (regs -> swizzled LDS)
            int row = vd + d;
            uint2 p;
            p.x = (unsigned)vrC[0].e[d] | ((unsigned)vrC[1].e[d] << 16);
            p.y = (unsigned)vrC[2].e[d] | ((unsigned)vrC[3].e[d] << 16);
            *(uint2*)&Vt[row * 128 + (vk ^ ((row & 7) << 3))] = p;
        }
        __syncthreads();
        #pragma unroll
        for (int f = 0; f < 2; f++) {
            // S^T = K·Q^T for q-fragment f: 8 subtiles of 16 keys; D[key][qrow]
            f32x4 sc[8];
            PRIO1();
            #pragma unroll
            for (int sub = 0; sub < 8; sub++) {
                const u16* kr = &Ksh[(sub * 16 + l16) * 64];
                bf16x8 kf0 = as_bf16x8(*(const uint4*)(kr + ((quad * 8) ^ sw)));
                bf16x8 kf1 = as_bf16x8(*(const uint4*)(kr + ((32 + quad * 8) ^ sw)));
                f32x4 s = __builtin_amdgcn_mfma_f32_16x16x32_bf16(kf0, qf[f][0], f4zero(), 0, 0, 0);
                sc[sub] = __builtin_amdgcn_mfma_f32_16x16x32_bf16(kf1, qf[f][1], s, 0, 0, 0);
            }
            PRIO0();
            if (f == 0 && kt + 1 < nkt) {   // T14: issue next V tile loads; hide under SM+PV
                #pragma unroll
                for (int j = 0; j < 4; j++) {
                    int key = min(kbase + 128 + vk + j, S - 1);
                    vrN[j].u = *(const uint4*)(Vp + (size_t)key * ldkv + vd);
                }
            }
            if (!full) {
                #pragma unroll
                for (int sub = 0; sub < 8; sub++)
                    #pragma unroll
                    for (int r = 0; r < 4; r++)
                        if (kbase + sub * 16 + quad * 4 + r >= S) sc[sub][r] = -1e30f;
            }
            float psum = 0.f;
            #pragma unroll
            for (int sub = 0; sub < 8; sub++) {
                float p0 = __builtin_amdgcn_exp2f(sc[sub][0]);
                float p1 = __builtin_amdgcn_exp2f(sc[sub][1]);
                float p2 = __builtin_amdgcn_exp2f(sc[sub][2]);
                float p3 = __builtin_amdgcn_exp2f(sc[sub][3]);
                psum += (p0 + p1) + (p2 + p3);
                uint2 pk;
                pk.x = __builtin_amdgcn_perm(__float_as_uint(p1), __float_as_uint(p0), 0x07060302);
                pk.y = __builtin_amdgcn_perm(__float_as_uint(p3), __float_as_uint(p2), 0x07060302);
                *(uint2*)&Pb[w][(f * 16 + l16) * 128 + ((sub * 16 + quad * 4) ^ sw)] = pk;
            }
            l_l[f] += psum;
        }
        // PV: P[32q x 128k] (A, own-wave LDS) x V^T (B); vf shared across both q-fragments
        PRIO1();
        #pragma unroll
        for (int kk = 0; kk < 4; kk++) {
            bf16x8 pf0 = as_bf16x8(*(const uint4*)&Pb[w][(l16) * 128 + ((kk * 32 + quad * 8) ^ sw)]);
            bf16x8 pf1 = as_bf16x8(*(const uint4*)&Pb[w][(16 + l16) * 128 + ((kk * 32 + quad * 8) ^ sw)]);
            #pragma unroll
            for (int dt = 0; dt < 4; dt++) {
                bf16x8 vf = as_bf16x8(*(const uint4*)&Vt[(dt * 16 + l16) * 128 + ((kk * 32 + quad * 8) ^ sw)]);
                o_acc[0][dt] = __builtin_amdgcn_mfma_f32_16x16x32_bf16(pf0, vf, o_acc[0][dt], 0, 0, 0);
                o_acc[1][dt] = __builtin_amdgcn_mfma_f32_16x16x32_bf16(pf1, vf, o_acc[1][dt], 0, 0, 0);
            }
        }
        PRIO0();
        #pragma unroll
        for (int j = 0; j < 4; j++) vrC[j] = vrN[j];
    }
    #pragma unroll
    for (int f = 0; f < 2; f++) {
        float l_tot = l_l[f];
        l_tot += __shfl_xor(l_tot, 16, 64);
        l_tot += __shfl_xor(l_tot, 32, 64);
        #pragma unroll
        for (int r = 0; r < 4; r++) {
            float lr = __shfl(l_tot, quad * 4 + r, 64);
            float invl = (lr > 0.f) ? (1.f / lr) : 0.f;
            int gq = q0 + w * 32 + f * 16 + quad * 4 + r;
            #pragma unroll
            for (int dt = 0; dt < 4; dt++) {
                O[((size_t)b * NTOK + gq) * ldq + h * DHEAD + dt * 16 + l16] = f2bf(o_acc[f][dt][r] * invl);
            }
        }
    }
}

extern "C" void kernel_launch(void* const* d_in, const int* in_sizes, int n_in,
                              void* d_out, int out_size, void* d_ws, size_t ws_size,
                              hipStream_t stream) {
    const float* x   = (const float*)d_in[0];
    const float* ctx = (const float*)d_in[1];
    const float* Wq1 = (const float*)d_in[2];
    const float* Wk1 = (const float*)d_in[3];
    const float* Wv1 = (const float*)d_in[4];
    const float* Wo1 = (const float*)d_in[5];
    const float* bo1 = (const float*)d_in[6];
    const float* Wq2 = (const float*)d_in[7];
    const float* Wk2 = (const float*)d_in[8];
    const float* Wv2 = (const float*)d_in[9];
    const float* Wo2 = (const float*)d_in[10];
    const float* bo2 = (const float*)d_in[11];
    const float* Wp  = (const float*)d_in[12];
    const float* bp  = (const float*)d_in[13];
    const float* Wf  = (const float*)d_in[14];
    const float* bfb = (const float*)d_in[15];
    const float* g1  = (const float*)d_in[16];
    const float* b1  = (const float*)d_in[17];
    const float* g2  = (const float*)d_in[18];
    const float* b2  = (const float*)d_in[19];
    const float* g3  = (const float*)d_in[20];
    const float* b3  = (const float*)d_in[21];
    float* out = (float*)d_out;

    const int M = BATCH * NTOK;      // 8192
    const int Mc = BATCH * SCROSS;   // 308
    u16* ws = (u16*)d_ws;
    size_t o = 0;
    u16* WqT1 = ws + o; o += (size_t)DIM * DIM;        // contiguous QKV weight stack:
    u16* WkT1 = ws + o; o += (size_t)DIM * DIM;
    u16* WvT1 = ws + o; o += (size_t)DIM * DIM;
    u16* WoT1 = ws + o; o += (size_t)DIM * DIM;
    u16* WqT2 = ws + o; o += (size_t)DIM * DIM;
    u16* WoT2 = ws + o; o += (size_t)DIM * DIM;
    u16* WkT2 = ws + o; o += (size_t)DIM * CTXD;       // contiguous KV2 stack
    u16* WvT2 = ws + o; o += (size_t)DIM * CTXD;
    u16* WpT  = ws + o; o += (size_t)(2 * FFIN) * DIM; // geglu-interleaved a/gate rows
    u16* WfT  = ws + o; o += (size_t)DIM * FFIN;
    u16* ctxb = ws + o; o += (size_t)Mc * CTXD;
    u16* KVc  = ws + o; o += (size_t)Mc * 2048;        // cross K|V, ld 2048
    u16* P    = ws + o; o += (size_t)M * DIM;          // LN outputs
    u16* QKV  = ws + o; o += (size_t)M * 3072;         // Q|K|V / attn-out, ld 3072
    u16* reg2 = ws + o; o += (size_t)M * DIM * 2;      // X1 (fp32) ; tail of gb
    float* X1 = (float*)reg2;
    u16* gb = QKV;                                     // [8192][4096] overlays QKV+first half of reg2

    dim3 blk(256);
    const float qscale = 0.125f * 1.4426950408889634f;  // 1/sqrt(64) * log2(e)

    wt_k<<<dim3(16, 16), blk, 0, stream>>>(Wq1, WqT1, DIM, DIM, qscale, 0);
    wt_k<<<dim3(16, 16), blk, 0, stream>>>(Wk1, WkT1, DIM, DIM, 1.f, 0);
    wt_k<<<dim3(16, 16), blk, 0, stream>>>(Wv1, WvT1, DIM, DIM, 1.f, 0);
    wt_k<<<dim3(16, 16), blk, 0, stream>>>(Wo1, WoT1, DIM, DIM, 1.f, 0);
    wt_k<<<dim3(16, 16), blk, 0, stream>>>(Wq2, WqT2, DIM, DIM, qscale, 0);
    wt_k<<<dim3(16, 16), blk, 0, stream>>>(Wo2, WoT2, DIM, DIM, 1.f, 0);
    wt_k<<<dim3(12, 16), blk, 0, stream>>>(Wk2, WkT2, CTXD, DIM, 1.f, 0);
    wt_k<<<dim3(12, 16), blk, 0, stream>>>(Wv2, WvT2, CTXD, DIM, 1.f, 0);
    wt_k<<<dim3(16, 128), blk, 0, stream>>>(Wp, WpT, DIM, 2 * FFIN, 1.f, 1);   // interleaved
    wt_k<<<dim3(64, 16), blk, 0, stream>>>(Wf, WfT, FFIN, DIM, 1.f, 0);
    cvt_k<<<dim3((Mc * CTXD / 4 + 255) / 256), blk, 0, stream>>>(ctx, ctxb, Mc * CTXD / 4);

    // --- self attention ---
    ln_k<<<dim3(M), blk, 0, stream>>>(x, g1, b1, P);
    gemm256<12, 3072, 0><<<dim3(32 * 12), dim3(512), 0, stream>>>(P, WqT1, nullptr, QKV);
    attn_k<<<dim3(BATCH * HEADS, NTOK / 128), blk, 0, stream>>>(
        QKV, 3072, QKV + 1024, QKV + 2048, 3072, QKV, NTOK);
    gemm128<float, true><<<dim3(M / 128, DIM / 128), blk, 0, stream>>>(
        QKV, 3072, WoT1, bo1, x, X1, DIM, M, DIM, DIM);

    // --- cross attention ---
    ln_k<<<dim3(M), blk, 0, stream>>>(X1, g2, b2, P);
    gemm128<u16, false><<<dim3(M / 128, DIM / 128), blk, 0, stream>>>(
        P, DIM, WqT2, nullptr, nullptr, QKV, 3072, M, DIM, DIM);
    gemm128<u16, false><<<dim3((Mc + 127) / 128, 2048 / 128), blk, 0, stream>>>(
        ctxb, CTXD, WkT2, nullptr, nullptr, KVc, 2048, Mc, 2048, CTXD);
    attn_k<<<dim3(BATCH * HEADS, NTOK / 128), blk, 0, stream>>>(
        QKV, 3072, KVc, KVc + 1024, 2048, QKV, SCROSS);
    gemm128<float, true><<<dim3(M / 128, DIM / 128), blk, 0, stream>>>(
        QKV, 3072, WoT2, bo2, X1, out, DIM, M, DIM, DIM);

    // --- GEGLU FF (overlapped-read Wp+geglu -> gb, then Wf with residual) ---
    ln_k<<<dim3(M), blk, 0, stream>>>(out, g3, b3, P);
    gemm256<32, 4096, 1><<<dim3(32 * 32), dim3(512), 0, stream>>>(P, WpT, bp, gb);
    gemm128<float, true><<<dim3(M / 128, DIM / 128), blk, 0, stream>>>(
        gb, FFIN, WfT, bfb, out, out, DIM, M, DIM, FFIN);
}